// Round 1
// baseline (391.076 us; speedup 1.0000x reference)
//
#include <hip/hip_runtime.h>
#include <math.h>

#define N_  32
#define T_  8192
#define D_  64
#define K_  64
#define CHUNKS 16
#define TOK_PER_BLOCK (T_ / CHUNKS)   // 512
#define TB 64                         // tokens per LDS batch
#define NBATCH (TOK_PER_BLOCK / TB)   // 8
#define STATS_PER_N (K_ + 2 * K_ * D_) // 8256

__device__ __forceinline__ float lane_bcast(float v, int l) {
    return __uint_as_float(__builtin_amdgcn_readlane(__float_as_uint(v), l));
}

// ---------------------------------------------------------------------------
// prep: A[k] = 2 log w_k - 0.5*sum_d(log c + mu^2/c);  bT[d][k]=mu/c; gT[d][k]=-0.5/c
// (transposed so the main kernel's per-lane row loads are coalesced)
// ---------------------------------------------------------------------------
__global__ void prep_kernel(const float* __restrict__ w, const float* __restrict__ mu,
                            const float* __restrict__ cv, float* __restrict__ Ap,
                            float* __restrict__ bT, float* __restrict__ gT) {
    int tid = threadIdx.x;
    for (int e = tid; e < K_ * D_; e += blockDim.x) {
        int k = e >> 6, d = e & 63;
        float c = cv[e];
        bT[d * K_ + k] = mu[e] / c;
        gT[d * K_ + k] = -0.5f / c;
    }
    if (tid < K_) {
        int k = tid;
        float acc = 0.f;
        for (int d = 0; d < D_; ++d) {
            int idx = k * D_ + d;
            float c = cv[idx], m = mu[idx];
            acc += logf(c) + m * m / c;
        }
        Ap[k] = 2.f * logf(w[k]) - 0.5f * acc;
    }
}

// ---------------------------------------------------------------------------
// main: fused posterior + pooled stats. grid = (CHUNKS, N), block = 256 (4 waves).
// Phase A: wave-per-token logits (lane=k, b/g rows in 128 VGPRs, x via readlane),
//          wave-shuffle softmax, stage p and x to LDS.
// Phase B: 4x4-per-thread register-tiled  s1 += p x^T,  s2 += p (x^2)^T.
// Block-end: atomicAdd partials into global stats.
// ---------------------------------------------------------------------------
__launch_bounds__(256, 2)
__global__ void main_kernel(const float* __restrict__ x, const float* __restrict__ Ap,
                            const float* __restrict__ bT, const float* __restrict__ gT,
                            float* __restrict__ stats) {
    __shared__ float xs[TB][D_];   // 16 KB
    __shared__ float ps[TB][K_];   // 16 KB

    const int tid  = threadIdx.x;
    const int lane = tid & 63;
    const int wv   = tid >> 6;     // wave 0..3
    const int chunk = blockIdx.x;
    const int n     = blockIdx.y;

    // per-lane (lane = k) rows of b and g, kept in registers for all tokens
    float bR[64], gR[64];
#pragma unroll
    for (int d = 0; d < 64; ++d) {
        bR[d] = bT[d * 64 + lane];   // coalesced: lane contiguous
        gR[d] = gT[d * 64 + lane];
    }
    const float aR = Ap[lane];

    // Phase-B accumulators: thread (ki,dj) owns k in [ki*4,ki*4+4), d in [dj*4,dj*4+4)
    const int ki = tid >> 4;   // 0..15
    const int dj = tid & 15;   // 0..15
    float a1[4][4], a2[4][4];
#pragma unroll
    for (int a = 0; a < 4; ++a)
#pragma unroll
        for (int b = 0; b < 4; ++b) { a1[a][b] = 0.f; a2[a][b] = 0.f; }
    float s0acc = 0.f;

    const size_t xbase = ((size_t)n * T_ + (size_t)chunk * TOK_PER_BLOCK) * D_;

    for (int batch = 0; batch < NBATCH; ++batch) {
        // ---------------- Phase A ----------------
        {
            const int t0 = wv * 16;                     // this wave's 16 tokens
            size_t base = xbase + (size_t)(batch * TB + t0) * D_ + lane;
            float xq = x[base];                         // x[t][lane], coalesced
            for (int i = 0; i < 16; ++i) {
                float xq_n = (i < 15) ? x[base + (size_t)(i + 1) * D_] : 0.f;
                const int t = t0 + i;
                xs[t][lane] = xq;
                float logit = aR;
#pragma unroll
                for (int d = 0; d < 64; ++d) {
                    float xb = lane_bcast(xq, d);
                    logit = fmaf(xb, bR[d], logit);
                    logit = fmaf(xb * xb, gR[d], logit);
                }
                // softmax over the 64 lanes (= 64 components)
                float m = logit;
#pragma unroll
                for (int off = 32; off > 0; off >>= 1)
                    m = fmaxf(m, __shfl_xor(m, off, 64));
                float e = __expf(logit - m);
                float s = e;
#pragma unroll
                for (int off = 32; off > 0; off >>= 1)
                    s += __shfl_xor(s, off, 64);
                float p = e / s;
                ps[t][lane] = p;
                s0acc += p;
                xq = xq_n;
            }
        }
        __syncthreads();
        // ---------------- Phase B ----------------
        for (int t = 0; t < TB; ++t) {
            const float4 pv = *(const float4*)&ps[t][ki * 4];
            const float4 xv = *(const float4*)&xs[t][dj * 4];
            const float px[4] = {pv.x, pv.y, pv.z, pv.w};
            const float xx[4] = {xv.x, xv.y, xv.z, xv.w};
#pragma unroll
            for (int b = 0; b < 4; ++b) {
                const float x2 = xx[b] * xx[b];
#pragma unroll
                for (int a = 0; a < 4; ++a) {
                    a1[a][b] = fmaf(px[a], xx[b], a1[a][b]);
                    a2[a][b] = fmaf(px[a], x2,   a2[a][b]);
                }
            }
        }
        __syncthreads();
    }

    // -------- flush partials --------
    float* sb = stats + (size_t)n * STATS_PER_N;
    atomicAdd(&sb[lane], s0acc);   // s0
#pragma unroll
    for (int a = 0; a < 4; ++a)
#pragma unroll
        for (int b = 0; b < 4; ++b) {
            const int idx = (ki * 4 + a) * 64 + dj * 4 + b;
            atomicAdd(&sb[64 + idx],        a1[a][b]);   // s1
            atomicAdd(&sb[64 + 4096 + idx], a2[a][b]);   // s2
        }
}

// ---------------------------------------------------------------------------
// finalize: v0/v1/v2, signed sqrt, L2 normalize per n. grid = N, block = 256.
// ---------------------------------------------------------------------------
__global__ void fin_kernel(const float* __restrict__ w, const float* __restrict__ mu,
                           const float* __restrict__ cv, const float* __restrict__ stats,
                           float* __restrict__ out) {
    __shared__ float us[STATS_PER_N];   // 33 KB
    __shared__ float red[4];
    const int n   = blockIdx.x;
    const int tid = threadIdx.x;
    const float* sb = stats + (size_t)n * STATS_PER_N;

    float ss = 0.f;
    for (int e = tid; e < STATS_PER_N; e += 256) {
        const int k = e / 129;
        const int r = e - k * 129;
        const float wv  = w[k];
        const float s0v = sb[k];
        float v;
        if (r == 0) {
            v = (s0v - (float)T_ * wv) * rsqrtf(wv);
        } else if (r < 65) {
            const int idx = k * 64 + (r - 1);
            v = (sb[64 + idx] - mu[idx] * s0v) * rsqrtf(wv * cv[idx]);
        } else {
            const int idx = k * 64 + (r - 65);
            const float m_ = mu[idx], c_ = cv[idx];
            const float s1v = sb[64 + idx], s2v = sb[64 + 4096 + idx];
            v = (s2v - 2.f * m_ * s1v + (m_ * m_ - c_) * s0v) * (rsqrtf(2.f * wv) / c_);
        }
        const float u = (v >= 0.f) ? sqrtf(v) : -sqrtf(-v);
        us[e] = u;
        ss = fmaf(u, u, ss);
    }
#pragma unroll
    for (int off = 32; off > 0; off >>= 1) ss += __shfl_xor(ss, off, 64);
    if ((tid & 63) == 0) red[tid >> 6] = ss;
    __syncthreads();
    const float tot = red[0] + red[1] + red[2] + red[3];
    const float rn = rsqrtf(tot);
    for (int e = tid; e < STATS_PER_N; e += 256)
        out[(size_t)n * STATS_PER_N + e] = us[e] * rn;
}

// ---------------------------------------------------------------------------
extern "C" void kernel_launch(void* const* d_in, const int* in_sizes, int n_in,
                              void* d_out, int out_size, void* d_ws, size_t ws_size,
                              hipStream_t stream) {
    const float* x  = (const float*)d_in[0];
    const float* w  = (const float*)d_in[1];
    const float* mu = (const float*)d_in[2];
    const float* cv = (const float*)d_in[3];
    float* out = (float*)d_out;

    // workspace layout (floats): stats[N*8256] | A[64] | bT[4096] | gT[4096]
    float* stats = (float*)d_ws;
    float* Ap = stats + (size_t)N_ * STATS_PER_N;
    float* bT = Ap + K_;
    float* gT = bT + K_ * D_;

    // ws is re-poisoned before every call: zero the accumulators each launch
    hipMemsetAsync(stats, 0, (size_t)N_ * STATS_PER_N * sizeof(float), stream);

    prep_kernel<<<1, 256, 0, stream>>>(w, mu, cv, Ap, bT, gT);
    main_kernel<<<dim3(CHUNKS, N_), 256, 0, stream>>>(x, Ap, bT, gT, stats);
    fin_kernel<<<N_, 256, 0, stream>>>(w, mu, cv, stats, out);
}